// Round 6
// baseline (213.999 us; speedup 1.0000x reference)
//
#include <hip/hip_runtime.h>
#include <math.h>

// Problem constants (B=8, T=4096, D=1024, G=2, N=320, Cd=512)
#define M_ROWS 32768   // B*T
#define KDIM   1024    // D
#define GN     640     // G*N
#define NGRP   2
#define NCODES 320
#define CD     512

#define BM 64            // rows per block
#define BK 32            // k-tile
#define NT (KDIM / BK)   // 32
#define THREADS 256      // 4 waves: 2 (M) x 2 (N)
#define SLAB 10240       // bytes per (tile, quarter) B slab
#define NBUF 4           // LDS ring buffers (40 KB total)

typedef __attribute__((ext_vector_type(8))) short bf16x8;   // 8 bf16 = 4 VGPR
typedef __attribute__((ext_vector_type(4))) float f32x4;

__device__ __forceinline__ unsigned short f2bf(float f) {
    unsigned u = __builtin_bit_cast(unsigned, f);
    return (unsigned short)((u + 0x7FFFu + ((u >> 16) & 1u)) >> 16);  // RNE
}
__device__ __forceinline__ unsigned pk2(float lo, float hi) {
    return (unsigned)f2bf(lo) | ((unsigned)f2bf(hi) << 16);
}
// async global->LDS; LDS dest = wave-uniform base + lane*width
__device__ __forceinline__ void gll16(const void* g, void* l) {
    __builtin_amdgcn_global_load_lds(
        (const __attribute__((address_space(1))) unsigned int*)g,
        (__attribute__((address_space(3))) unsigned int*)l, 16, 0, 0);
}
__device__ __forceinline__ void gll4(const void* g, void* l) {
    __builtin_amdgcn_global_load_lds(
        (const __attribute__((address_space(1))) unsigned int*)g,
        (__attribute__((address_space(3))) unsigned int*)l, 4, 0, 0);
}

// ---- prepass: W[k][GN] fp32 -> Wt3 bf16 laid out so a wave's B-frag ds_read
// is LINEAR: slab(t,qq) holds 10 blocks of 1KB; within block c16:
// chunk index = ks*16 + l15  (k = t*32+ks*8+j, col = qq*160+c16*16+l15).
// Also zeroes argmax keys and the counts histogram.
__global__ __launch_bounds__(256) void prep_kernel(const float* __restrict__ W,
                                                   unsigned short* __restrict__ Wt3,
                                                   unsigned long long* __restrict__ keys,
                                                   int* __restrict__ counts) {
    const int k = blockIdx.x;                    // 0..1023
    const int t = k >> 5, ks = (k >> 3) & 3, j = k & 7;
    for (int c = threadIdx.x; c < GN; c += 256) {
        int qq = c / 160;
        int cl = c % 160;
        int c16 = cl >> 4, l15 = cl & 15;
        size_t idx = (size_t)(t * 4 + qq) * 5120 + c16 * 512 + (ks * 16 + l15) * 8 + j;
        Wt3[idx] = f2bf(W[(size_t)k * GN + c]);
    }
    int gtid = blockIdx.x * 256 + threadIdx.x;
    if (gtid < M_ROWS * NGRP) keys[gtid] = 0ull;
    if (blockIdx.x == 0)
        for (int i = threadIdx.x; i < GN; i += 256) counts[i] = 0;
}

// ---- quarter-width MFMA GEMM + argmax; counted-vmcnt pipeline, 1 barrier/tile.
__global__ __launch_bounds__(THREADS, 4) void gemm_argmax(
    const float* __restrict__ x,              // [M, K] fp32
    const float* __restrict__ gumbel,         // [M, GN] fp32
    const unsigned short* __restrict__ Wt3,   // retiled bf16 (prep_kernel)
    const float* __restrict__ bias,           // [GN]
    unsigned long long* __restrict__ keys)    // [M, G] packed argmax
{
    __shared__ __align__(16) char Bs[NBUF * SLAB];   // 40 KB ring

    const int tid  = threadIdx.x;
    const int wid  = tid >> 6;       // 0..3
    const int lane = tid & 63;
    const int l15  = lane & 15;
    const int l4   = lane >> 4;      // k-slot
    const int wn   = wid & 1;        // col half: 80 cols
    const int wm   = wid >> 1;       // row half: 32 rows

    // block decode: bid = xcd + 8*(qq + 4*rt_local); quarters share an XCD
    const int b    = blockIdx.x;
    const int xcd  = b & 7;
    const int l    = b >> 3;
    const int qq   = l & 3;                   // column quarter
    const int rt   = xcd * 64 + (l >> 2);     // row tile 0..511
    const int row0 = rt * BM;

    f32x4 acc[2][5];
#pragma unroll
    for (int mf = 0; mf < 2; ++mf)
#pragma unroll
        for (int nf = 0; nf < 5; ++nf) acc[mf][nf] = (f32x4){0.f, 0.f, 0.f, 0.f};

    // A: per-lane register loads; lane serves rows (wm*32 + l15) and (+16), k-slice l4*8
    const float* ap0 = x + (size_t)(row0 + wm * 32 + l15) * KDIM + l4 * 8;
    const float* ap1 = ap0 + 16 * KDIM;
    // B staging: this wave's 2560B chunk of each slab
    const int woff = wid * 2560;
    const char* bsrc0 = (const char*)Wt3 + (size_t)qq * SLAB + woff;

#define STAGE_B(t, bufsel) do {                                        \
        const char* s_ = bsrc0 + (size_t)(t) * (4 * SLAB);             \
        char* d_ = Bs + (bufsel) * SLAB + woff;                        \
        gll16(s_ + (size_t)lane * 16,        d_);                      \
        gll16(s_ + 1024 + (size_t)lane * 16, d_ + 1024);               \
        gll4 (s_ + 2048 + (size_t)lane * 4,  d_ + 2048);               \
        gll4 (s_ + 2304 + (size_t)lane * 4,  d_ + 2304);               \
    } while (0)

#define LOAD_A(t, dst) do {                                            \
        const float* p0_ = ap0 + (size_t)(t) * BK;                     \
        const float* p1_ = ap1 + (size_t)(t) * BK;                     \
        dst[0] = *reinterpret_cast<const float4*>(p0_);                \
        dst[1] = *reinterpret_cast<const float4*>(p0_ + 4);            \
        dst[2] = *reinterpret_cast<const float4*>(p1_);                \
        dst[3] = *reinterpret_cast<const float4*>(p1_ + 4);            \
    } while (0)

#define COMPUTE(bufsel, aCur) do {                                     \
        union { bf16x8 v; unsigned u[4]; } wA0, wA1;                   \
        wA0.u[0] = pk2(aCur[0].x, aCur[0].y);                          \
        wA0.u[1] = pk2(aCur[0].z, aCur[0].w);                          \
        wA0.u[2] = pk2(aCur[1].x, aCur[1].y);                          \
        wA0.u[3] = pk2(aCur[1].z, aCur[1].w);                          \
        wA1.u[0] = pk2(aCur[2].x, aCur[2].y);                          \
        wA1.u[1] = pk2(aCur[2].z, aCur[2].w);                          \
        wA1.u[2] = pk2(aCur[3].x, aCur[3].y);                          \
        wA1.u[3] = pk2(aCur[3].z, aCur[3].w);                          \
        const char* bb = Bs + (bufsel) * SLAB + wn * 5120;             \
        _Pragma("unroll")                                              \
        for (int nf = 0; nf < 5; ++nf) {                               \
            bf16x8 bfr = *reinterpret_cast<const bf16x8*>(             \
                bb + nf * 1024 + (size_t)lane * 16);                   \
            acc[0][nf] = __builtin_amdgcn_mfma_f32_16x16x32_bf16(      \
                wA0.v, bfr, acc[0][nf], 0, 0, 0);                      \
            acc[1][nf] = __builtin_amdgcn_mfma_f32_16x16x32_bf16(      \
                wA1.v, bfr, acc[1][nf], 0, 0, 0);                      \
        }                                                              \
    } while (0)

#define SYNC_TILE() do {                                               \
        asm volatile("s_waitcnt vmcnt(12)" ::: "memory");              \
        __builtin_amdgcn_s_barrier();                                  \
        __builtin_amdgcn_sched_barrier(0);                             \
    } while (0)

    float4 aA[4], aB[4];
    // prologue: B 2-deep, A 1-deep (issue order matters for vmcnt counting)
    STAGE_B(0, 0);
    STAGE_B(1, 1);
    LOAD_A(0, aA);

    for (int jj = 0; jj < NT; jj += 2) {
        // body jj: cur = aA
        LOAD_A((jj + 1) & (NT - 1), aB);
        STAGE_B((jj + 2) & (NT - 1), (jj + 2) & 3);
        SYNC_TILE();
        COMPUTE(jj & 3, aA);
        // body jj+1: cur = aB
        LOAD_A((jj + 2) & (NT - 1), aA);
        STAGE_B((jj + 3) & (NT - 1), (jj + 3) & 3);
        SYNC_TILE();
        COMPUTE((jj + 1) & 3, aB);
    }

    // ---- epilogue: + bias + gumbel, argmax over this wave's 80 cols,
    // packed 64-bit atomicMax across the 8 partial owners of each (row, group).
    const int g     = qq >> 1;
    const int hbase = (qq & 1) * 160 + wn * 80;   // n-offset within group
    float bv[5];
#pragma unroll
    for (int nf = 0; nf < 5; ++nf)
        bv[nf] = bias[g * NCODES + hbase + nf * 16 + l15];
#pragma unroll
    for (int mf = 0; mf < 2; ++mf) {
#pragma unroll
        for (int j = 0; j < 4; ++j) {
            const int lr = wm * 32 + mf * 16 + l4 * 4 + j;   // C/D: row = l4*4 + reg
            const size_t r = row0 + lr;
            const float* grow = gumbel + r * GN + g * NCODES;
            float best = -INFINITY;
            int bn = 0;
#pragma unroll
            for (int nf = 0; nf < 5; ++nf) {
                int n = hbase + nf * 16 + l15;
                float v = acc[mf][nf][j] + bv[nf] + grow[n];
                if (v > best) { best = v; bn = n; }   // nf ascending -> first max kept
            }
#pragma unroll
            for (int m = 1; m < 16; m <<= 1) {
                float ov = __shfl_xor(best, m, 64);
                int   on = __shfl_xor(bn, m, 64);
                if (ov > best || (ov == best && on < bn)) { best = ov; bn = on; }
            }
            if (l15 == 0) {
                unsigned ub = __builtin_bit_cast(unsigned, best);
                unsigned su = (ub & 0x80000000u) ? ~ub : (ub | 0x80000000u);
                unsigned long long key =
                    ((unsigned long long)su << 32) | (unsigned)(NCODES - 1 - bn);
                atomicMax(&keys[r * NGRP + g], key);
            }
        }
    }
#undef STAGE_B
#undef LOAD_A
#undef COMPUTE
#undef SYNC_TILE
}

// ---- pure-BW gather + histogram: 8 rows per block
__global__ __launch_bounds__(256) void gather_kernel(
    const unsigned long long* __restrict__ keys,
    const float* __restrict__ codebook,
    int* __restrict__ counts,
    float* __restrict__ out)
{
    __shared__ int ns[8][2];
    const int t  = threadIdx.x;
    const int rb = blockIdx.x * 8;
    if (t < 16) {
        int lr = t >> 1, g = t & 1;
        unsigned long long key = keys[(size_t)(rb + lr) * NGRP + g];
        int n = NCODES - 1 - (int)(key & 0xFFFFFFFFull);
        ns[lr][g] = n;
        atomicAdd(&counts[g * NCODES + n], 1);
    }
    __syncthreads();
#pragma unroll
    for (int s = 0; s < 8; ++s) {
        int fi = t + 256 * s;        // 0..2047
        int lr = fi >> 8, q = fi & 255;
        int g = q >> 7, d4 = q & 127;
        int n = ns[lr][g];
        float4 cv = *reinterpret_cast<const float4*>(
            &codebook[((size_t)g * NCODES + n) * CD + d4 * 4]);
        *reinterpret_cast<float4*>(&out[(size_t)(rb + lr) * KDIM + q * 4]) = cv;
    }
}

__global__ void loss_kernel(const int* __restrict__ counts, float* __restrict__ out_loss) {
    __shared__ float red[256];
    float sum = 0.0f;
    for (int i = threadIdx.x; i < GN; i += 256) {
        float avg = (float)counts[i] * (1.0f / (float)M_ROWS);
        sum += avg * logf(avg + 1e-7f);
    }
    red[threadIdx.x] = sum;
    __syncthreads();
    for (int s = 128; s > 0; s >>= 1) {
        if (threadIdx.x < s) red[threadIdx.x] += red[threadIdx.x + s];
        __syncthreads();
    }
    if (threadIdx.x == 0) out_loss[0] = -red[0] * (1.0f / (float)NGRP);
}

extern "C" void kernel_launch(void* const* d_in, const int* in_sizes, int n_in,
                              void* d_out, int out_size, void* d_ws, size_t ws_size,
                              hipStream_t stream) {
    const float* x        = (const float*)d_in[0];
    const float* gumbel   = (const float*)d_in[1];
    const float* codebook = (const float*)d_in[2];
    const float* W        = (const float*)d_in[3];
    const float* bias     = (const float*)d_in[4];
    float* out = (float*)d_out;

    unsigned short* Wt3 = (unsigned short*)d_ws;                              // 1.25 MB
    unsigned long long* keys = (unsigned long long*)((char*)d_ws + 1310720);  // 512 KB
    int* counts = (int*)((char*)d_ws + 1310720 + 524288);                     // 2.5 KB

    prep_kernel<<<dim3(KDIM), dim3(256), 0, stream>>>(W, Wt3, keys, counts);
    gemm_argmax<<<dim3(2048), dim3(THREADS), 0, stream>>>(
        x, gumbel, Wt3, bias, keys);
    gather_kernel<<<dim3(M_ROWS / 8), dim3(256), 0, stream>>>(
        keys, codebook, counts, out);
    loss_kernel<<<dim3(1), dim3(256), 0, stream>>>(
        counts, out + (size_t)M_ROWS * KDIM);
}

// Round 7
// 172.048 us; speedup vs baseline: 1.2438x; 1.2438x over previous
//
#include <hip/hip_runtime.h>
#include <math.h>

// Problem constants (B=8, T=4096, D=1024, G=2, N=320, Cd=512)
#define M_ROWS 32768   // B*T
#define KDIM   1024    // D
#define GN     640     // G*N
#define NGRP   2
#define NCODES 320
#define CD     512

#define BM 64            // rows per block
#define BK 32            // k-tile
#define NT (KDIM / BK)   // 32
#define THREADS 256      // 4 waves: 2 (M) x 2 (N)
#define SLAB 20480       // bytes per (tile, group) B slab: 20 c16-blocks x 64 chunks x 16B

typedef __attribute__((ext_vector_type(8))) short bf16x8;   // 8 bf16 = 4 VGPR
typedef __attribute__((ext_vector_type(4))) float f32x4;

__device__ __forceinline__ unsigned short f2bf(float f) {
    unsigned u = __builtin_bit_cast(unsigned, f);
    return (unsigned short)((u + 0x7FFFu + ((u >> 16) & 1u)) >> 16);  // RNE
}
__device__ __forceinline__ unsigned pk2(float lo, float hi) {
    return (unsigned)f2bf(lo) | ((unsigned)f2bf(hi) << 16);
}
// async global->LDS, 16B/lane; LDS dest = wave-uniform base + lane*16
__device__ __forceinline__ void gll16(const void* g, void* l) {
    __builtin_amdgcn_global_load_lds(
        (const __attribute__((address_space(1))) unsigned int*)g,
        (__attribute__((address_space(3))) unsigned int*)l, 16, 0, 0);
}

// ---- prepass: W[k][GN] fp32 -> Wt4 bf16, laid out so a wave's B-frag ds_read is
// LINEAR 1KB: slab(t,g) = [c16(20)][chunk(64)][8 bf16], chunk = ks*16 + colmod16,
// k = t*32 + ks*8 + j, col-in-group = c16*16 + colmod16. Zeroes counts too.
__global__ __launch_bounds__(256) void prep_kernel(const float* __restrict__ W,
                                                   unsigned short* __restrict__ Wt4,
                                                   int* __restrict__ counts) {
    const int k = blockIdx.x;                    // 0..1023
    const int t = k >> 5, ks = (k >> 3) & 3, j = k & 7;
    for (int c = threadIdx.x; c < GN; c += 256) {
        int g   = c / NCODES;
        int cl  = c % NCODES;
        int c16 = cl >> 4, cm = cl & 15;
        size_t idx = (size_t)(t * 2 + g) * 10240 + c16 * 512 + (ks * 16 + cm) * 8 + j;
        Wt4[idx] = f2bf(W[(size_t)k * GN + c]);
    }
    if (blockIdx.x == 0)
        for (int i = threadIdx.x; i < GN; i += 256) counts[i] = 0;
}

// ---- fused half-width MFMA GEMM + argmax + counts + gather.
// Block = (row-tile, group): 64 rows x 320 cols; 4 waves = 2M x 2N.
// 1024 blocks, group pair of a row-tile clustered on one XCD.
__global__ __launch_bounds__(THREADS) void gemm_fused(
    const float* __restrict__ x,              // [M, K] fp32
    const float* __restrict__ gumbel,         // [M, GN] fp32
    const float* __restrict__ codebook,       // [G, N, CD] fp32
    const unsigned short* __restrict__ Wt4,   // retiled bf16 (prep_kernel)
    const float* __restrict__ bias,           // [GN]
    float* __restrict__ out,                  // [M, G*CD] fp32 (+ loss slot)
    int* __restrict__ counts)                 // [GN]
{
    __shared__ __align__(16) char Bs[SLAB];   // 20 KB single-buffered B tile
    __shared__ float pv[2][BM];
    __shared__ int   pi[2][BM];
    __shared__ int   idx_s[BM];

    const int tid  = threadIdx.x;
    const int wid  = tid >> 6;       // 0..3
    const int lane = tid & 63;
    const int l15  = lane & 15;
    const int l4   = lane >> 4;      // k-slot
    const int wn   = wid & 1;        // col half: 160 cols
    const int wm   = wid >> 1;       // row half: 32 rows

    // block decode: bid = xcd + 8*(g + 2*rt_local); the two groups of a row
    // tile are consecutive on the same XCD (x rows L2-shared).
    const int b    = blockIdx.x;
    const int xcd  = b & 7;
    const int q    = b >> 3;
    const int g    = q & 1;
    const int rt   = xcd * 64 + (q >> 1);     // row tile 0..511
    const int row0 = rt * BM;

    f32x4 acc[2][10];
#pragma unroll
    for (int mf = 0; mf < 2; ++mf)
#pragma unroll
        for (int nf = 0; nf < 10; ++nf) acc[mf][nf] = (f32x4){0.f, 0.f, 0.f, 0.f};

    // A: per-lane register loads; lane serves rows (wm*32+l15) and (+16), k-slice l4*8
    const float* ap0 = x + (size_t)(row0 + wm * 32 + l15) * KDIM + l4 * 8;
    const float* ap1 = ap0 + 16 * KDIM;
    // B: per-lane global src; wave wid stages bytes wid*5120..+5119 of each slab
    const char* bsrc0 = (const char*)Wt4 + (size_t)g * SLAB + wid * 5120 + (size_t)lane * 16;

#define STAGE_B(t) do {                                                 \
        const char* s_ = bsrc0 + (size_t)(t) * (2 * SLAB);              \
        char* d_ = Bs + wid * 5120;                                     \
        gll16(s_,        d_);                                           \
        gll16(s_ + 1024, d_ + 1024);                                    \
        gll16(s_ + 2048, d_ + 2048);                                    \
        gll16(s_ + 3072, d_ + 3072);                                    \
        gll16(s_ + 4096, d_ + 4096);                                    \
    } while (0)

#define LOAD_A(t, dst) do {                                             \
        const float* p0_ = ap0 + (size_t)(t) * BK;                      \
        const float* p1_ = ap1 + (size_t)(t) * BK;                      \
        dst[0] = *reinterpret_cast<const float4*>(p0_);                 \
        dst[1] = *reinterpret_cast<const float4*>(p0_ + 4);             \
        dst[2] = *reinterpret_cast<const float4*>(p1_);                 \
        dst[3] = *reinterpret_cast<const float4*>(p1_ + 4);             \
    } while (0)

#define CONV_A(src, a0_, a1_) do {                                      \
        union { bf16x8 v; unsigned u[4]; } w0_, w1_;                    \
        w0_.u[0] = pk2(src[0].x, src[0].y);                             \
        w0_.u[1] = pk2(src[0].z, src[0].w);                             \
        w0_.u[2] = pk2(src[1].x, src[1].y);                             \
        w0_.u[3] = pk2(src[1].z, src[1].w);                             \
        w1_.u[0] = pk2(src[2].x, src[2].y);                             \
        w1_.u[1] = pk2(src[2].z, src[2].w);                             \
        w1_.u[2] = pk2(src[3].x, src[3].y);                             \
        w1_.u[3] = pk2(src[3].z, src[3].w);                             \
        a0_ = w0_.v; a1_ = w1_.v;                                       \
    } while (0)

    // prologue: stage tile 0 (B DMA + A regs), one drain
    float4 nx[4];
    bf16x8 af0, af1;
    STAGE_B(0);
    LOAD_A(0, nx);
    CONV_A(nx, af0, af1);
    __syncthreads();   // drains vmcnt: tile 0 in LDS

    for (int t = 0; t < NT; ++t) {
        if (t + 1 < NT) LOAD_A(t + 1, nx);   // A(t+1) flies during compute
        const char* bb = Bs + wn * 10240;
#pragma unroll
        for (int nf = 0; nf < 10; ++nf) {
            bf16x8 bfr = *reinterpret_cast<const bf16x8*>(
                bb + nf * 1024 + (size_t)lane * 16);   // linear 1KB wave read
            acc[0][nf] = __builtin_amdgcn_mfma_f32_16x16x32_bf16(af0, bfr, acc[0][nf], 0, 0, 0);
            acc[1][nf] = __builtin_amdgcn_mfma_f32_16x16x32_bf16(af1, bfr, acc[1][nf], 0, 0, 0);
        }
        if (t + 1 < NT) {
            __syncthreads();          // all waves done reading Bs(t)
            STAGE_B(t + 1);
            CONV_A(nx, af0, af1);
            __syncthreads();          // drains DMA: Bs(t+1) resident
        }
    }

    // ---- epilogue: + bias + gumbel, per-row argmax over this wave's 160 cols
    // C/D layout: col = l15, row-in-frag = l4*4 + reg
#pragma unroll
    for (int mf = 0; mf < 2; ++mf) {
#pragma unroll
        for (int j = 0; j < 4; ++j) {
            const int lr = wm * 32 + mf * 16 + l4 * 4 + j;
            const size_t r = row0 + lr;
            const float* grow = gumbel + r * GN + g * NCODES;
            const float* brow = bias + g * NCODES;
            float best = -INFINITY;
            int bn = 0;
#pragma unroll
            for (int nf = 0; nf < 10; ++nf) {
                int n = wn * 160 + nf * 16 + l15;
                float v = acc[mf][nf][j] + brow[n] + grow[n];
                if (v > best) { best = v; bn = n; }   // nf ascending -> first max kept
            }
#pragma unroll
            for (int m = 1; m < 16; m <<= 1) {
                float ov = __shfl_xor(best, m, 64);
                int   on = __shfl_xor(bn, m, 64);
                if (ov > best || (ov == best && on < bn)) { best = ov; bn = on; }
            }
            if (l15 == 0) { pv[wn][lr] = best; pi[wn][lr] = bn; }
        }
    }
    __syncthreads();

    // combine halves: wn=1 cols all > wn=0 cols, strict > keeps lower index (np.argmax)
    if (tid < BM) {
        float v0 = pv[0][tid], v1 = pv[1][tid];
        int n = (v1 > v0) ? pi[1][tid] : pi[0][tid];
        idx_s[tid] = n;
        atomicAdd(&counts[g * NCODES + n], 1);
    }
    __syncthreads();

    // ---- gather: this block's half of out: 64 rows x 512 floats, coalesced
#pragma unroll
    for (int s = 0; s < 32; ++s) {
        int fi = tid + THREADS * s;   // 0..8191
        int lr = fi >> 7;             // /128 float4 per row
        int d4 = fi & 127;
        int n  = idx_s[lr];
        float4 cv = *reinterpret_cast<const float4*>(
            &codebook[((size_t)g * NCODES + n) * CD + d4 * 4]);
        *reinterpret_cast<float4*>(
            &out[(size_t)(row0 + lr) * KDIM + (size_t)g * CD + d4 * 4]) = cv;
    }
#undef STAGE_B
#undef LOAD_A
#undef CONV_A
}

__global__ void loss_kernel(const int* __restrict__ counts, float* __restrict__ out_loss) {
    __shared__ float red[256];
    float sum = 0.0f;
    for (int i = threadIdx.x; i < GN; i += 256) {
        float avg = (float)counts[i] * (1.0f / (float)M_ROWS);
        sum += avg * logf(avg + 1e-7f);
    }
    red[threadIdx.x] = sum;
    __syncthreads();
    for (int s = 128; s > 0; s >>= 1) {
        if (threadIdx.x < s) red[threadIdx.x] += red[threadIdx.x + s];
        __syncthreads();
    }
    if (threadIdx.x == 0) out_loss[0] = -red[0] * (1.0f / (float)NGRP);
}

extern "C" void kernel_launch(void* const* d_in, const int* in_sizes, int n_in,
                              void* d_out, int out_size, void* d_ws, size_t ws_size,
                              hipStream_t stream) {
    const float* x        = (const float*)d_in[0];
    const float* gumbel   = (const float*)d_in[1];
    const float* codebook = (const float*)d_in[2];
    const float* W        = (const float*)d_in[3];
    const float* bias     = (const float*)d_in[4];
    float* out = (float*)d_out;

    unsigned short* Wt4 = (unsigned short*)d_ws;              // 1.31 MB retiled
    int* counts = (int*)((char*)d_ws + 1310720 + 256);        // 2.5 KB

    prep_kernel<<<dim3(KDIM), dim3(256), 0, stream>>>(W, Wt4, counts);
    gemm_fused<<<dim3(1024), dim3(THREADS), 0, stream>>>(
        x, gumbel, codebook, Wt4, bias, out, counts);
    loss_kernel<<<dim3(1), dim3(256), 0, stream>>>(
        counts, out + (size_t)M_ROWS * KDIM);
}